// Round 8
// baseline (489.665 us; speedup 1.0000x reference)
//
#include <hip/hip_runtime.h>
#include <math.h>

#define B_ 64
#define N_ 2048
#define O_ 32
#define I_ 16
#define D_ 32
#define OD_ 1024

typedef __attribute__((ext_vector_type(8))) short bf16x8;
typedef __attribute__((ext_vector_type(4))) float f32x4;

union FragU { unsigned u[4]; uint4 v; bf16x8 f; };

// Raw workgroup barrier that does NOT drain vmcnt: orders LDS (lgkmcnt) only.
// Safe here: global loads crossing it are consumed only by the issuing wave.
// The "memory" clobber pins issue order of surrounding memory ops.
__device__ __forceinline__ void barrier_lds() {
  asm volatile("s_waitcnt lgkmcnt(0)\n\ts_barrier" ::: "memory");
}

__device__ __forceinline__ void dk_split(float f, unsigned &h, unsigned &l) {
  unsigned u = __float_as_uint(f);
  h = u & 0xffff0000u;
  float lo = f - __uint_as_float(h);
  l = __float_as_uint(lo) >> 16;
}

__device__ __forceinline__ void dk_split16(float f, unsigned short &h,
                                           unsigned short &l) {
  unsigned u = __float_as_uint(f);
  unsigned hu = u & 0xffff0000u;
  h = (unsigned short)(u >> 16);
  float lo = f - __uint_as_float(hu);
  l = (unsigned short)(__float_as_uint(lo) >> 16);
}

__device__ __forceinline__ unsigned pk(unsigned short e0, unsigned short e1) {
  return (unsigned)e0 | ((unsigned)e1 << 16);
}

// ---- merged prep: blocks [0,8192) pack W -> WP, [8192,8704) pack x -> XP ----
// WP u4 idx = (((n*32+o)*2 + dhalf)*4 + sel*2 + qp)*16 + c   (sel0=hi, sel1=lo)
// XP u4 idx = (((bg*2048+n)*2 + sel)*2 + qp)*16 + c ; b = bg*16 + c
__global__ __launch_bounds__(256) void prep_all(const float* __restrict__ W,
                                                const float* __restrict__ x,
                                                uint4* __restrict__ WP,
                                                uint4* __restrict__ XP) {
  if (blockIdx.x < 8192) {
    int t = blockIdx.x * 256 + threadIdx.x;  // 2,097,152 = n*o*d
    int d = t & 31, o = (t >> 5) & 31, n = t >> 10;
    const float* wp = W + ((size_t)(n * O_ + o) * I_) * D_ + d;
    unsigned short hh[I_], ll[I_];
#pragma unroll
    for (int i = 0; i < I_; ++i) dk_split16(wp[i * D_], hh[i], ll[i]);
    int c = d & 15, dhalf = d >> 4;
    size_t base = ((size_t)(n * O_ + o) * 2 + dhalf) * 4;
#pragma unroll
    for (int sel = 0; sel < 2; ++sel) {
      const unsigned short* e = sel ? ll : hh;
#pragma unroll
      for (int qp = 0; qp < 2; ++qp) {
        uint4 u;
        u.x = pk(e[qp * 8 + 0], e[qp * 8 + 1]);
        u.y = pk(e[qp * 8 + 2], e[qp * 8 + 3]);
        u.z = pk(e[qp * 8 + 4], e[qp * 8 + 5]);
        u.w = pk(e[qp * 8 + 6], e[qp * 8 + 7]);
        WP[(base + sel * 2 + qp) * 16 + c] = u;
      }
    }
  } else {
    int t = (blockIdx.x - 8192) * 256 + threadIdx.x;  // 131,072
    int c = t & 15, n = (t >> 4) & 2047, bg = t >> 15;
    const float* xp = x + ((size_t)(bg * 16 + c) * N_ + n) * I_;
    unsigned short hh[I_], ll[I_];
#pragma unroll
    for (int i = 0; i < I_; ++i) dk_split16(xp[i], hh[i], ll[i]);
    size_t base = ((size_t)bg * N_ + n) * 4;
#pragma unroll
    for (int sel = 0; sel < 2; ++sel) {
      const unsigned short* e = sel ? ll : hh;
#pragma unroll
      for (int qp = 0; qp < 2; ++qp) {
        uint4 u;
        u.x = pk(e[qp * 8 + 0], e[qp * 8 + 1]);
        u.y = pk(e[qp * 8 + 2], e[qp * 8 + 3]);
        u.z = pk(e[qp * 8 + 4], e[qp * 8 + 5]);
        u.w = pk(e[qp * 8 + 6], e[qp * 8 + 7]);
        XP[(base + sel * 2 + qp) * 16 + c] = u;
      }
    }
  }
}

// ---- fused routing pass: prefetch-next-n + no-drain barriers ----
// 16 waves/block; wave w covers o = 2w,2w+1 (4 od-tiles). Block = 16 b x
// 1024 od cols, grid (chunks, 4 b-groups). Per n: issue n+1's 6 loads FIRST,
// MFMA on n (vmcnt waits only n's loads), then logits/softmax/reweight with
// raw lgkm-only barriers -> n+1's loads stay in flight through the barriers.
template <int UNIFORM>
__global__ __launch_bounds__(1024, 4) void mfma_pass5(
    const uint4* __restrict__ XP, const uint4* __restrict__ WP,
    const float* __restrict__ v, float* __restrict__ partial, int NC) {
  const int tid = threadIdx.x;
  const int lane = tid & 63;
  const int w = tid >> 6;       // o-pair index 0..15
  const int q = lane >> 4;
  const int c = lane & 15;
  const int qp = q & 1;
  const int ch = blockIdx.x;
  const int bg = blockIdx.y;

  __shared__ float ls_logit[16 * O_];
  __shared__ float ls_c[16 * O_];

  f32x4 s_t[4];
#pragma unroll
  for (int ct = 0; ct < 4; ++ct) s_t[ct] = (f32x4){0.f, 0.f, 0.f, 0.f};

  // hoisted v fragments (loop-invariant)
  float vreg[4][4];
  if (!UNIFORM) {
#pragma unroll
    for (int ct = 0; ct < 4; ++ct) {
      int odc = (2 * w + (ct >> 1)) * 32 + (ct & 1) * 16 + c;
#pragma unroll
      for (int r = 0; r < 4; ++r)
        vreg[ct][r] = v[(size_t)(bg * 16 + q * 4 + r) * OD_ + odc];
    }
  }

  const int n0 = ch * NC;
  // XP u4 idx = bg*N*64 + n*64 + sel*32 + qp*16 + c
  const uint4* xbase = XP + ((size_t)bg * N_) * 64 + qp * 16 + c;
  // WP u4 idx = n*4096 + o*128 + (o_l*2+dh)*64 + rec*16 + c ; rec==q via +lane
  const uint4* wbase0 = WP + (size_t)(2 * w) * 128 + lane;

  // prologue: load fragments for n0
  FragU cah, cal, cb[4];
  cah.v = xbase[(size_t)n0 * 64];
  cal.v = xbase[(size_t)n0 * 64 + 32];
#pragma unroll
  for (int ct = 0; ct < 4; ++ct)
    cb[ct].v = wbase0[(size_t)n0 * 4096 + ct * 64];

  for (int nl = 0; nl < NC; ++nl) {
    const size_t np = (size_t)(n0 + ((nl + 1 < NC) ? nl + 1 : nl));

    // ---- issue next-n loads FIRST (fly through MFMA + softmax + barriers) ----
    FragU nah, nal, nb[4];
    nah.v = xbase[np * 64];
    nal.v = xbase[np * 64 + 32];
#pragma unroll
    for (int ct = 0; ct < 4; ++ct)
      nb[ct].v = wbase0[np * 4096 + ct * 64];
    asm volatile("" ::: "memory");  // pin issue order: prefetch before compute

    // ---- MFMA on current fragments ----
    f32x4 u_t[4];
#pragma unroll
    for (int ct = 0; ct < 4; ++ct) {
      if (UNIFORM) {
        s_t[ct] = __builtin_amdgcn_mfma_f32_16x16x32_bf16(cah.f, cb[ct].f, s_t[ct], 0, 0, 0);
        s_t[ct] = __builtin_amdgcn_mfma_f32_16x16x32_bf16(cal.f, cb[ct].f, s_t[ct], 0, 0, 0);
      } else {
        f32x4 acc = (f32x4){0.f, 0.f, 0.f, 0.f};
        acc = __builtin_amdgcn_mfma_f32_16x16x32_bf16(cah.f, cb[ct].f, acc, 0, 0, 0);
        u_t[ct] = __builtin_amdgcn_mfma_f32_16x16x32_bf16(cal.f, cb[ct].f, acc, 0, 0, 0);
      }
    }

    if (!UNIFORM) {
      // ---- logits: logit[b,o] = sum_d u*v ----
#pragma unroll
      for (int op = 0; op < 2; ++op) {
        float lg[4] = {0.f, 0.f, 0.f, 0.f};
#pragma unroll
        for (int hf = 0; hf < 2; ++hf) {
          int ct = op * 2 + hf;
#pragma unroll
          for (int r = 0; r < 4; ++r)
            lg[r] = fmaf(u_t[ct][r], vreg[ct][r], lg[r]);
        }
#pragma unroll
        for (int r = 0; r < 4; ++r) {
#pragma unroll
          for (int m = 1; m < 16; m <<= 1) lg[r] += __shfl_xor(lg[r], m);
        }
        if (c == 0) {
#pragma unroll
          for (int r = 0; r < 4; ++r)
            ls_logit[(q * 4 + r) * O_ + 2 * w + op] = lg[r];
        }
      }
      barrier_lds();  // no vmcnt drain: prefetch stays in flight
      // ---- softmax: 512 rows (16 b x 32 o) on first 512 threads ----
      if (tid < 512) {
        int b_l = tid >> 5, o = tid & 31;
        float l = ls_logit[b_l * O_ + o];
        float mx = l;
#pragma unroll
        for (int m = 16; m >= 1; m >>= 1) mx = fmaxf(mx, __shfl_xor(mx, m));
        float e = __expf(l - mx);
        float sm = e;
#pragma unroll
        for (int m = 16; m >= 1; m >>= 1) sm += __shfl_xor(sm, m);
        ls_c[b_l * O_ + o] = e / sm;
      }
      barrier_lds();
      // ---- s += c * u ----
#pragma unroll
      for (int ct = 0; ct < 4; ++ct) {
        int o = 2 * w + (ct >> 1);
#pragma unroll
        for (int r = 0; r < 4; ++r) {
          float cc = ls_c[(q * 4 + r) * O_ + o];
          s_t[ct][r] = fmaf(cc, u_t[ct][r], s_t[ct][r]);
        }
      }
    }

    // rotate
    cah = nah;
    cal = nal;
#pragma unroll
    for (int ct = 0; ct < 4; ++ct) cb[ct] = nb[ct];
  }

  const float scale = UNIFORM ? (1.f / 32.f) : 1.f;
#pragma unroll
  for (int ct = 0; ct < 4; ++ct) {
    int odc = (2 * w + (ct >> 1)) * 32 + (ct & 1) * 16 + c;
#pragma unroll
    for (int r = 0; r < 4; ++r) {
      partial[((size_t)ch * B_ + bg * 16 + q * 4 + r) * OD_ + odc] =
          s_t[ct][r] * scale;
    }
  }
}

// ---- fallback (round-2 path, used only if ws too small for WP/XP) ----
template <int UNIFORM>
__global__ __launch_bounds__(512, 4) void mfma_pass_fb(
    const float* __restrict__ x, const float* __restrict__ W,
    const float* __restrict__ v, float* __restrict__ partial, int NC) {
  const int tid = threadIdx.x;
  const int lane = tid & 63;
  const int cg = tid >> 6;
  const int q = lane >> 4;
  const int c = lane & 15;
  const int ch = blockIdx.x;
  const int bg = blockIdx.y;

  __shared__ float ls_logit[16 * O_];
  __shared__ float ls_c[16 * O_];

  f32x4 s_t[8];
#pragma unroll
  for (int ct = 0; ct < 8; ++ct) s_t[ct] = (f32x4){0.f, 0.f, 0.f, 0.f};

  const int n0 = ch * NC;
  const int ih = (q & 1) * 8;
  const float* xrow = x + ((size_t)(bg * 16 + c) * N_) * I_ + ih;

  for (int nl = 0; nl < NC; ++nl) {
    const int n = n0 + nl;
    const float* xp = xrow + (size_t)n * I_;
    float4 xv0 = *(const float4*)xp;
    float4 xv1 = *(const float4*)(xp + 4);
    float xv[8] = {xv0.x, xv0.y, xv0.z, xv0.w, xv1.x, xv1.y, xv1.z, xv1.w};
    FragU a1;
#pragma unroll
    for (int p = 0; p < 4; ++p) {
      unsigned h0, l0, h1, l1;
      dk_split(xv[2 * p], h0, l0);
      dk_split(xv[2 * p + 1], h1, l1);
      a1.u[p] = (q < 2) ? ((h0 >> 16) | h1) : (l0 | (l1 << 16));
    }
    f32x4 u_t[8];
#pragma unroll
    for (int ct = 0; ct < 8; ++ct) {
      const int o = cg * 4 + (ct >> 1);
      const int d = (ct & 1) * 16 + c;
      const float* wp = W + (((size_t)n * O_ + o) * I_ + ih) * D_ + d;
      FragU b1, b2;
#pragma unroll
      for (int p = 0; p < 4; ++p) {
        unsigned h0, l0, h1, l1;
        dk_split(wp[(2 * p) * D_], h0, l0);
        dk_split(wp[(2 * p + 1) * D_], h1, l1);
        b1.u[p] = (h0 >> 16) | h1;
        b2.u[p] = l0 | (l1 << 16);
      }
      if (UNIFORM) {
        s_t[ct] = __builtin_amdgcn_mfma_f32_16x16x32_bf16(a1.f, b1.f, s_t[ct], 0, 0, 0);
        s_t[ct] = __builtin_amdgcn_mfma_f32_16x16x32_bf16(a1.f, b2.f, s_t[ct], 0, 0, 0);
      } else {
        f32x4 acc = (f32x4){0.f, 0.f, 0.f, 0.f};
        acc = __builtin_amdgcn_mfma_f32_16x16x32_bf16(a1.f, b1.f, acc, 0, 0, 0);
        u_t[ct] = __builtin_amdgcn_mfma_f32_16x16x32_bf16(a1.f, b2.f, acc, 0, 0, 0);
      }
    }
    if (!UNIFORM) {
#pragma unroll
      for (int ol = 0; ol < 4; ++ol) {
        float lg[4] = {0.f, 0.f, 0.f, 0.f};
#pragma unroll
        for (int hf = 0; hf < 2; ++hf) {
          int ct = ol * 2 + hf;
          int odc = cg * 128 + ct * 16 + c;
#pragma unroll
          for (int r = 0; r < 4; ++r)
            lg[r] = fmaf(u_t[ct][r], v[(size_t)(bg * 16 + q * 4 + r) * OD_ + odc], lg[r]);
        }
#pragma unroll
        for (int r = 0; r < 4; ++r) {
#pragma unroll
          for (int m = 1; m < 16; m <<= 1) lg[r] += __shfl_xor(lg[r], m);
        }
        if (c == 0) {
#pragma unroll
          for (int r = 0; r < 4; ++r)
            ls_logit[(q * 4 + r) * O_ + cg * 4 + ol] = lg[r];
        }
      }
      __syncthreads();
      {
        int b_l = tid >> 5, o = tid & 31;
        float l = ls_logit[b_l * O_ + o];
        float mx = l;
#pragma unroll
        for (int m = 16; m >= 1; m >>= 1) mx = fmaxf(mx, __shfl_xor(mx, m));
        float e = __expf(l - mx);
        float sm = e;
#pragma unroll
        for (int m = 16; m >= 1; m >>= 1) sm += __shfl_xor(sm, m);
        ls_c[b_l * O_ + o] = e / sm;
      }
      __syncthreads();
#pragma unroll
      for (int ol = 0; ol < 4; ++ol) {
        int o = cg * 4 + ol;
        float cc[4];
#pragma unroll
        for (int r = 0; r < 4; ++r) cc[r] = ls_c[(q * 4 + r) * O_ + o];
#pragma unroll
        for (int hf = 0; hf < 2; ++hf) {
          int ct = ol * 2 + hf;
#pragma unroll
          for (int r = 0; r < 4; ++r)
            s_t[ct][r] = fmaf(cc[r], u_t[ct][r], s_t[ct][r]);
        }
      }
    }
  }

  const float scale = UNIFORM ? (1.f / 32.f) : 1.f;
#pragma unroll
  for (int ct = 0; ct < 8; ++ct) {
#pragma unroll
    for (int r = 0; r < 4; ++r) {
      partial[((size_t)ch * B_ + bg * 16 + q * 4 + r) * OD_ + cg * 128 + ct * 16 + c] =
          s_t[ct][r] * scale;
    }
  }
}

// Sum partials over chunks (float4, unrolled), squash along d.
// out = (prev ? prev : 0) + squash(s); 8 threads per (b,o) row.
__global__ __launch_bounds__(256) void reduce_squash(
    const float4* __restrict__ part, int chunks,
    const float4* __restrict__ prev, float4* __restrict__ out) {
  int g4 = blockIdx.x * 256 + threadIdx.x;  // 16384 total
  float4 s = make_float4(0.f, 0.f, 0.f, 0.f);
#pragma unroll 4
  for (int ch = 0; ch < chunks; ++ch) {
    float4 p = part[(size_t)ch * 16384 + g4];
    s.x += p.x; s.y += p.y; s.z += p.z; s.w += p.w;
  }
  float sq = s.x * s.x + s.y * s.y + s.z * s.z + s.w * s.w;
#pragma unroll
  for (int m = 4; m >= 1; m >>= 1) sq += __shfl_xor(sq, m, 8);
  float scale = sq / ((1.f + sq) * (sqrtf(sq) + 1e-6f));
  float4 r = make_float4(s.x * scale, s.y * scale, s.z * scale, s.w * scale);
  if (prev) {
    float4 p = prev[g4];
    r.x += p.x; r.y += p.y; r.z += p.z; r.w += p.w;
  }
  out[g4] = r;
}

extern "C" void kernel_launch(void* const* d_in, const int* in_sizes, int n_in,
                              void* d_out, int out_size, void* d_ws,
                              size_t ws_size, hipStream_t stream) {
  const float* x = (const float*)d_in[0];
  const float* W = (const float*)d_in[1];
  float* out = (float*)d_out;

  const size_t XP_FLOATS = 4ull * 2048 * 4 * 16 * 4;        // 2,097,152
  const size_t WP_FLOATS = 2048ull * 32 * 2 * 4 * 16 * 4;   // 33,554,432

  float* v1 = (float*)d_ws;
  float* vsum = v1 + 65536;
  float* partial = vsum + 65536;

  int chunks = 128;
  while (chunks > 8 &&
         (131072 + (size_t)chunks * 65536 + XP_FLOATS + WP_FLOATS) * 4 > ws_size)
    chunks >>= 1;
  bool packed_path =
      (131072 + (size_t)chunks * 65536 + XP_FLOATS + WP_FLOATS) * 4 <= ws_size;

  if (packed_path) {
    uint4* XP = (uint4*)(partial + (size_t)chunks * 65536);
    uint4* WP = XP + XP_FLOATS / 4;
    int NC = N_ / chunks;
    dim3 grid(chunks, 4);

    prep_all<<<8704, 256, 0, stream>>>(W, x, WP, XP);

    mfma_pass5<1><<<grid, 1024, 0, stream>>>(XP, WP, nullptr, partial, NC);
    reduce_squash<<<64, 256, 0, stream>>>((const float4*)partial, chunks,
                                          nullptr, (float4*)v1);
    mfma_pass5<0><<<grid, 1024, 0, stream>>>(XP, WP, v1, partial, NC);
    reduce_squash<<<64, 256, 0, stream>>>((const float4*)partial, chunks,
                                          (const float4*)v1, (float4*)vsum);
    mfma_pass5<0><<<grid, 1024, 0, stream>>>(XP, WP, vsum, partial, NC);
    reduce_squash<<<64, 256, 0, stream>>>((const float4*)partial, chunks,
                                          nullptr, (float4*)out);
  } else {
    chunks = 128;
    while (chunks > 1 && (131072 + (size_t)chunks * 65536) * 4 > ws_size)
      chunks >>= 1;
    int NC = N_ / chunks;
    dim3 grid(chunks, 4);

    mfma_pass_fb<1><<<grid, 512, 0, stream>>>(x, W, nullptr, partial, NC);
    reduce_squash<<<64, 256, 0, stream>>>((const float4*)partial, chunks,
                                          nullptr, (float4*)v1);
    mfma_pass_fb<0><<<grid, 512, 0, stream>>>(x, W, v1, partial, NC);
    reduce_squash<<<64, 256, 0, stream>>>((const float4*)partial, chunks,
                                          (const float4*)v1, (float4*)vsum);
    mfma_pass_fb<0><<<grid, 512, 0, stream>>>(x, W, vsum, partial, NC);
    reduce_squash<<<64, 256, 0, stream>>>((const float4*)partial, chunks,
                                          nullptr, (float4*)out);
  }
}

// Round 9
// 412.965 us; speedup vs baseline: 1.1857x; 1.1857x over previous
//
#include <hip/hip_runtime.h>
#include <math.h>

#define B_ 64
#define N_ 2048
#define O_ 32
#define I_ 16
#define D_ 32
#define OD_ 1024

typedef __attribute__((ext_vector_type(8))) short bf16x8;
typedef __attribute__((ext_vector_type(4))) float f32x4;

union FragU { unsigned u[4]; uint4 v; bf16x8 f; };

// lgkm-only barrier: does not drain vmcnt (global prefetches stay in flight).
__device__ __forceinline__ void barrier_lds() {
  asm volatile("s_waitcnt lgkmcnt(0)\n\ts_barrier" ::: "memory");
}

// ---- DPP cross-lane (VALU pipe, no LDS traffic) ----
template <int CTRL>
__device__ __forceinline__ float dpp_mov_f(float x) {
  return __int_as_float(
      __builtin_amdgcn_update_dpp(0, __float_as_int(x), CTRL, 0xf, 0xf, true));
}
// all-reduce sum over 16-lane row (dist 8,4 via row_ror; 2,1 via quad_perm)
__device__ __forceinline__ float row16_sum(float x) {
  x += dpp_mov_f<0x128>(x);  // row_ror:8
  x += dpp_mov_f<0x124>(x);  // row_ror:4
  x += dpp_mov_f<0x4e>(x);   // quad_perm [2,3,0,1]
  x += dpp_mov_f<0xb1>(x);   // quad_perm [1,0,3,2]
  return x;
}
__device__ __forceinline__ float grp32_max(float x) {
  x = fmaxf(x, dpp_mov_f<0xb1>(x));
  x = fmaxf(x, dpp_mov_f<0x4e>(x));
  x = fmaxf(x, dpp_mov_f<0x124>(x));
  x = fmaxf(x, dpp_mov_f<0x128>(x));
  x = fmaxf(x, __shfl_xor(x, 16));
  return x;
}
__device__ __forceinline__ float grp32_sum(float x) {
  x += dpp_mov_f<0xb1>(x);
  x += dpp_mov_f<0x4e>(x);
  x += dpp_mov_f<0x124>(x);
  x += dpp_mov_f<0x128>(x);
  x += __shfl_xor(x, 16);
  return x;
}

__device__ __forceinline__ void dk_split(float f, unsigned &h, unsigned &l) {
  unsigned u = __float_as_uint(f);
  h = u & 0xffff0000u;
  float lo = f - __uint_as_float(h);
  l = __float_as_uint(lo) >> 16;
}
__device__ __forceinline__ void dk_split16(float f, unsigned short &h,
                                           unsigned short &l) {
  unsigned u = __float_as_uint(f);
  unsigned hu = u & 0xffff0000u;
  h = (unsigned short)(u >> 16);
  float lo = f - __uint_as_float(hu);
  l = (unsigned short)(__float_as_uint(lo) >> 16);
}
__device__ __forceinline__ unsigned pk(unsigned short e0, unsigned short e1) {
  return (unsigned)e0 | ((unsigned)e1 << 16);
}

// ---- merged prep: blocks [0,8192) pack W -> WP, [8192,8704) pack x -> XP ----
// WP u4 idx = (((n*32+o)*2 + dhalf)*4 + sel*2 + qp)*16 + c   (sel0=hi, sel1=lo)
// XP u4 idx = (((bg*2048+n)*2 + sel)*2 + qp)*16 + c ; b = bg*16 + c
__global__ __launch_bounds__(256) void prep_all(const float* __restrict__ W,
                                                const float* __restrict__ x,
                                                uint4* __restrict__ WP,
                                                uint4* __restrict__ XP) {
  if (blockIdx.x < 8192) {
    int t = blockIdx.x * 256 + threadIdx.x;  // 2,097,152 = n*o*d
    int d = t & 31, o = (t >> 5) & 31, n = t >> 10;
    const float* wp = W + ((size_t)(n * O_ + o) * I_) * D_ + d;
    unsigned short hh[I_], ll[I_];
#pragma unroll
    for (int i = 0; i < I_; ++i) dk_split16(wp[i * D_], hh[i], ll[i]);
    int c = d & 15, dhalf = d >> 4;
    size_t base = ((size_t)(n * O_ + o) * 2 + dhalf) * 4;
#pragma unroll
    for (int sel = 0; sel < 2; ++sel) {
      const unsigned short* e = sel ? ll : hh;
#pragma unroll
      for (int qp = 0; qp < 2; ++qp) {
        uint4 u;
        u.x = pk(e[qp * 8 + 0], e[qp * 8 + 1]);
        u.y = pk(e[qp * 8 + 2], e[qp * 8 + 3]);
        u.z = pk(e[qp * 8 + 4], e[qp * 8 + 5]);
        u.w = pk(e[qp * 8 + 6], e[qp * 8 + 7]);
        WP[(base + sel * 2 + qp) * 16 + c] = u;
      }
    }
  } else {
    int t = (blockIdx.x - 8192) * 256 + threadIdx.x;  // 131,072
    int c = t & 15, n = (t >> 4) & 2047, bg = t >> 15;
    const float* xp = x + ((size_t)(bg * 16 + c) * N_ + n) * I_;
    unsigned short hh[I_], ll[I_];
#pragma unroll
    for (int i = 0; i < I_; ++i) dk_split16(xp[i], hh[i], ll[i]);
    size_t base = ((size_t)bg * N_ + n) * 4;
#pragma unroll
    for (int sel = 0; sel < 2; ++sel) {
      const unsigned short* e = sel ? ll : hh;
#pragma unroll
      for (int qp = 0; qp < 2; ++qp) {
        uint4 u;
        u.x = pk(e[qp * 8 + 0], e[qp * 8 + 1]);
        u.y = pk(e[qp * 8 + 2], e[qp * 8 + 3]);
        u.z = pk(e[qp * 8 + 4], e[qp * 8 + 5]);
        u.w = pk(e[qp * 8 + 6], e[qp * 8 + 7]);
        XP[(base + sel * 2 + qp) * 16 + c] = u;
      }
    }
  }
}

// ---- fused routing pass v6: 32-b block, XP in LDS, recompute-u, DPP ----
// Block = 32 b (bgl 0,1) x 1024 od x NC n. 16 waves; wave w owns o=2w,2w+1.
// grid (128 chunks, 2 b-halves) = 256 blocks = 1/CU. WP slice read by only
// 2 blocks GPU-wide (halved per-CU stream vs R8). u_hat recomputed in the
// reweight phase (2x MFMA, frees 32+ VGPRs). Reductions via DPP (VALU pipe).
template <int UNIFORM>
__global__ __launch_bounds__(1024, 4) void mfma_pass6(
    const uint4* __restrict__ XP, const uint4* __restrict__ WP,
    const float* __restrict__ v, float* __restrict__ partial, int NC) {
  const int tid = threadIdx.x;
  const int lane = tid & 63;
  const int w = tid >> 6;
  const int q = lane >> 4;
  const int c = lane & 15;
  const int qp = q & 1;
  const int ch = blockIdx.x;
  const int bgy = blockIdx.y;  // b in [bgy*32, bgy*32+32)

  __shared__ uint4 xps[2][16][4][16];  // [bgl][nl][rec][c] = 32 KB
  __shared__ float ls_logit[32 * O_];  // 4 KB
  __shared__ float ls_c[32 * O_];      // 4 KB

  const int n0 = ch * NC;

  // ---- stage XP (both b-groups, all NC n) into LDS, once ----
  {
    uint4* xf = (uint4*)xps;
    const int total = 2 * NC * 64;
    for (int l = tid; l < total; l += 1024) {
      int bgl = l / (NC * 64);
      int rest = l - bgl * (NC * 64);  // nl*64 + rec*16 + c
      xf[bgl * 1024 + rest] =
          XP[(size_t)(bgy * 2 + bgl) * 131072 + (size_t)n0 * 64 + rest];
    }
  }

  f32x4 s_t[2][4];
#pragma unroll
  for (int bgl = 0; bgl < 2; ++bgl)
#pragma unroll
    for (int ct = 0; ct < 4; ++ct) s_t[bgl][ct] = (f32x4){0.f, 0.f, 0.f, 0.f};

  // hoisted v fragments
  float vreg[2][4][4];
  if (!UNIFORM) {
#pragma unroll
    for (int bgl = 0; bgl < 2; ++bgl)
#pragma unroll
      for (int ct = 0; ct < 4; ++ct) {
        int odc = (2 * w + (ct >> 1)) * 32 + (ct & 1) * 16 + c;
#pragma unroll
        for (int r = 0; r < 4; ++r)
          vreg[bgl][ct][r] =
              v[(size_t)(bgy * 32 + bgl * 16 + q * 4 + r) * OD_ + odc];
      }
  }

  barrier_lds();  // xps ready (compiler inserts vmcnt wait before ds_write)

  // WP u4 idx = n*4096 + o*128 + dh*64 + q*16 + c ; wave's 4 tiles:
  const uint4* wbase = WP + (size_t)(2 * w) * 128 + lane;

  for (int nl = 0; nl < NC; ++nl) {
    const size_t n = (size_t)(n0 + nl);

    FragU cb[4];
#pragma unroll
    for (int ct = 0; ct < 4; ++ct) cb[ct].v = wbase[n * 4096 + ct * 64];

    if (UNIFORM) {
#pragma unroll
      for (int bgl = 0; bgl < 2; ++bgl) {
        FragU ah, al;
        ah.v = xps[bgl][nl][qp][c];
        al.v = xps[bgl][nl][2 + qp][c];
#pragma unroll
        for (int ct = 0; ct < 4; ++ct) {
          s_t[bgl][ct] = __builtin_amdgcn_mfma_f32_16x16x32_bf16(
              ah.f, cb[ct].f, s_t[bgl][ct], 0, 0, 0);
          s_t[bgl][ct] = __builtin_amdgcn_mfma_f32_16x16x32_bf16(
              al.f, cb[ct].f, s_t[bgl][ct], 0, 0, 0);
        }
      }
    } else {
      // ---- phase 1: u_hat (transient) -> logits ----
      float lg[2][2][4];
#pragma unroll
      for (int bgl = 0; bgl < 2; ++bgl)
#pragma unroll
        for (int ol = 0; ol < 2; ++ol)
#pragma unroll
          for (int r = 0; r < 4; ++r) lg[bgl][ol][r] = 0.f;
#pragma unroll
      for (int bgl = 0; bgl < 2; ++bgl) {
        FragU ah, al;
        ah.v = xps[bgl][nl][qp][c];
        al.v = xps[bgl][nl][2 + qp][c];
#pragma unroll
        for (int ct = 0; ct < 4; ++ct) {
          f32x4 acc = (f32x4){0.f, 0.f, 0.f, 0.f};
          acc = __builtin_amdgcn_mfma_f32_16x16x32_bf16(ah.f, cb[ct].f, acc, 0, 0, 0);
          f32x4 u = __builtin_amdgcn_mfma_f32_16x16x32_bf16(al.f, cb[ct].f, acc, 0, 0, 0);
          int ol = ct >> 1;
#pragma unroll
          for (int r = 0; r < 4; ++r)
            lg[bgl][ol][r] = fmaf(u[r], vreg[bgl][ct][r], lg[bgl][ol][r]);
        }
      }
      // reduce over the 16 c-lanes (DPP, VALU pipe) and publish
#pragma unroll
      for (int bgl = 0; bgl < 2; ++bgl)
#pragma unroll
        for (int ol = 0; ol < 2; ++ol)
#pragma unroll
          for (int r = 0; r < 4; ++r) lg[bgl][ol][r] = row16_sum(lg[bgl][ol][r]);
      if (c == 0) {
#pragma unroll
        for (int bgl = 0; bgl < 2; ++bgl)
#pragma unroll
          for (int ol = 0; ol < 2; ++ol)
#pragma unroll
            for (int r = 0; r < 4; ++r)
              ls_logit[(bgl * 16 + q * 4 + r) * O_ + 2 * w + ol] = lg[bgl][ol][r];
      }
      barrier_lds();
      // ---- phase 2: softmax, 1024 rows = 1024 threads (32 b x 32 o) ----
      {
        float l = ls_logit[tid];
        float mx = grp32_max(l);
        float e = __expf(l - mx);
        float sm = grp32_sum(e);
        ls_c[tid] = e / sm;
      }
      barrier_lds();
      // ---- phase 3: recompute u_hat, s += c*u ----
#pragma unroll
      for (int bgl = 0; bgl < 2; ++bgl) {
        FragU ah, al;
        ah.v = xps[bgl][nl][qp][c];
        al.v = xps[bgl][nl][2 + qp][c];
#pragma unroll
        for (int ct = 0; ct < 4; ++ct) {
          f32x4 acc = (f32x4){0.f, 0.f, 0.f, 0.f};
          acc = __builtin_amdgcn_mfma_f32_16x16x32_bf16(ah.f, cb[ct].f, acc, 0, 0, 0);
          f32x4 u = __builtin_amdgcn_mfma_f32_16x16x32_bf16(al.f, cb[ct].f, acc, 0, 0, 0);
          int o = 2 * w + (ct >> 1);
#pragma unroll
          for (int r = 0; r < 4; ++r) {
            float cc = ls_c[(bgl * 16 + q * 4 + r) * O_ + o];
            s_t[bgl][ct][r] = fmaf(cc, u[r], s_t[bgl][ct][r]);
          }
        }
      }
    }
  }

  const float scale = UNIFORM ? (1.f / 32.f) : 1.f;
#pragma unroll
  for (int bgl = 0; bgl < 2; ++bgl)
#pragma unroll
    for (int ct = 0; ct < 4; ++ct) {
      int odc = (2 * w + (ct >> 1)) * 32 + (ct & 1) * 16 + c;
#pragma unroll
      for (int r = 0; r < 4; ++r) {
        partial[((size_t)ch * B_ + bgy * 32 + bgl * 16 + q * 4 + r) * OD_ + odc] =
            s_t[bgl][ct][r] * scale;
      }
    }
}

// ---- fallback (round-2 path, used only if ws too small for WP/XP) ----
template <int UNIFORM>
__global__ __launch_bounds__(512, 4) void mfma_pass_fb(
    const float* __restrict__ x, const float* __restrict__ W,
    const float* __restrict__ v, float* __restrict__ partial, int NC) {
  const int tid = threadIdx.x;
  const int lane = tid & 63;
  const int cg = tid >> 6;
  const int q = lane >> 4;
  const int c = lane & 15;
  const int ch = blockIdx.x;
  const int bg = blockIdx.y;

  __shared__ float ls_logit[16 * O_];
  __shared__ float ls_c[16 * O_];

  f32x4 s_t[8];
#pragma unroll
  for (int ct = 0; ct < 8; ++ct) s_t[ct] = (f32x4){0.f, 0.f, 0.f, 0.f};

  const int n0 = ch * NC;
  const int ih = (q & 1) * 8;
  const float* xrow = x + ((size_t)(bg * 16 + c) * N_) * I_ + ih;

  for (int nl = 0; nl < NC; ++nl) {
    const int n = n0 + nl;
    const float* xp = xrow + (size_t)n * I_;
    float4 xv0 = *(const float4*)xp;
    float4 xv1 = *(const float4*)(xp + 4);
    float xv[8] = {xv0.x, xv0.y, xv0.z, xv0.w, xv1.x, xv1.y, xv1.z, xv1.w};
    FragU a1;
#pragma unroll
    for (int p = 0; p < 4; ++p) {
      unsigned h0, l0, h1, l1;
      dk_split(xv[2 * p], h0, l0);
      dk_split(xv[2 * p + 1], h1, l1);
      a1.u[p] = (q < 2) ? ((h0 >> 16) | h1) : (l0 | (l1 << 16));
    }
    f32x4 u_t[8];
#pragma unroll
    for (int ct = 0; ct < 8; ++ct) {
      const int o = cg * 4 + (ct >> 1);
      const int d = (ct & 1) * 16 + c;
      const float* wp = W + (((size_t)n * O_ + o) * I_ + ih) * D_ + d;
      FragU b1, b2;
#pragma unroll
      for (int p = 0; p < 4; ++p) {
        unsigned h0, l0, h1, l1;
        dk_split(wp[(2 * p) * D_], h0, l0);
        dk_split(wp[(2 * p + 1) * D_], h1, l1);
        b1.u[p] = (h0 >> 16) | h1;
        b2.u[p] = l0 | (l1 << 16);
      }
      if (UNIFORM) {
        s_t[ct] = __builtin_amdgcn_mfma_f32_16x16x32_bf16(a1.f, b1.f, s_t[ct], 0, 0, 0);
        s_t[ct] = __builtin_amdgcn_mfma_f32_16x16x32_bf16(a1.f, b2.f, s_t[ct], 0, 0, 0);
      } else {
        f32x4 acc = (f32x4){0.f, 0.f, 0.f, 0.f};
        acc = __builtin_amdgcn_mfma_f32_16x16x32_bf16(a1.f, b1.f, acc, 0, 0, 0);
        u_t[ct] = __builtin_amdgcn_mfma_f32_16x16x32_bf16(a1.f, b2.f, acc, 0, 0, 0);
      }
    }
    if (!UNIFORM) {
#pragma unroll
      for (int ol = 0; ol < 4; ++ol) {
        float lg[4] = {0.f, 0.f, 0.f, 0.f};
#pragma unroll
        for (int hf = 0; hf < 2; ++hf) {
          int ct = ol * 2 + hf;
          int odc = cg * 128 + ct * 16 + c;
#pragma unroll
          for (int r = 0; r < 4; ++r)
            lg[r] = fmaf(u_t[ct][r], v[(size_t)(bg * 16 + q * 4 + r) * OD_ + odc], lg[r]);
        }
#pragma unroll
        for (int r = 0; r < 4; ++r) {
#pragma unroll
          for (int m = 1; m < 16; m <<= 1) lg[r] += __shfl_xor(lg[r], m);
        }
        if (c == 0) {
#pragma unroll
          for (int r = 0; r < 4; ++r)
            ls_logit[(q * 4 + r) * O_ + cg * 4 + ol] = lg[r];
        }
      }
      __syncthreads();
      {
        int b_l = tid >> 5, o = tid & 31;
        float l = ls_logit[b_l * O_ + o];
        float mx = l;
#pragma unroll
        for (int m = 16; m >= 1; m >>= 1) mx = fmaxf(mx, __shfl_xor(mx, m));
        float e = __expf(l - mx);
        float sm = e;
#pragma unroll
        for (int m = 16; m >= 1; m >>= 1) sm += __shfl_xor(sm, m);
        ls_c[b_l * O_ + o] = e / sm;
      }
      __syncthreads();
#pragma unroll
      for (int ol = 0; ol < 4; ++ol) {
        int o = cg * 4 + ol;
        float cc[4];
#pragma unroll
        for (int r = 0; r < 4; ++r) cc[r] = ls_c[(q * 4 + r) * O_ + o];
#pragma unroll
        for (int hf = 0; hf < 2; ++hf) {
          int ct = ol * 2 + hf;
#pragma unroll
          for (int r = 0; r < 4; ++r)
            s_t[ct][r] = fmaf(cc[r], u_t[ct][r], s_t[ct][r]);
        }
      }
    }
  }

  const float scale = UNIFORM ? (1.f / 32.f) : 1.f;
#pragma unroll
  for (int ct = 0; ct < 8; ++ct) {
#pragma unroll
    for (int r = 0; r < 4; ++r) {
      partial[((size_t)ch * B_ + bg * 16 + q * 4 + r) * OD_ + cg * 128 + ct * 16 + c] =
          s_t[ct][r] * scale;
    }
  }
}

// ---- two-stage reduce: A) 256 blocks fold chunks 4x in place ----
// block qa=x>>6 sums part[qa*cq .. qa*cq+cq-1] -> part[qa*cq] (own range only)
__global__ __launch_bounds__(256) void reduce_stageA(float4* __restrict__ part,
                                                     int cq) {
  int qa = blockIdx.x >> 6;
  int g4 = (blockIdx.x & 63) * 256 + threadIdx.x;
  float4 s = make_float4(0.f, 0.f, 0.f, 0.f);
  for (int i = 0; i < cq; ++i) {
    float4 p = part[(size_t)(qa * cq + i) * 16384 + g4];
    s.x += p.x; s.y += p.y; s.z += p.z; s.w += p.w;
  }
  part[(size_t)(qa * cq) * 16384 + g4] = s;
}

// ---- B) sum the 4 folded rows, squash along d, add prev ----
__global__ __launch_bounds__(256) void reduce_stageB(
    const float4* __restrict__ part, int cq, const float4* __restrict__ prev,
    float4* __restrict__ out) {
  int g4 = blockIdx.x * 256 + threadIdx.x;  // 16384
  float4 s = make_float4(0.f, 0.f, 0.f, 0.f);
#pragma unroll
  for (int qa = 0; qa < 4; ++qa) {
    float4 p = part[(size_t)(qa * cq) * 16384 + g4];
    s.x += p.x; s.y += p.y; s.z += p.z; s.w += p.w;
  }
  float sq = s.x * s.x + s.y * s.y + s.z * s.z + s.w * s.w;
#pragma unroll
  for (int m = 4; m >= 1; m >>= 1) sq += __shfl_xor(sq, m, 8);
  float scale = sq / ((1.f + sq) * (sqrtf(sq) + 1e-6f));
  float4 r = make_float4(s.x * scale, s.y * scale, s.z * scale, s.w * scale);
  if (prev) {
    float4 p = prev[g4];
    r.x += p.x; r.y += p.y; r.z += p.z; r.w += p.w;
  }
  out[g4] = r;
}

// single-stage reduce (fallback path)
__global__ __launch_bounds__(256) void reduce_squash(
    const float4* __restrict__ part, int chunks,
    const float4* __restrict__ prev, float4* __restrict__ out) {
  int g4 = blockIdx.x * 256 + threadIdx.x;
  float4 s = make_float4(0.f, 0.f, 0.f, 0.f);
#pragma unroll 4
  for (int ch = 0; ch < chunks; ++ch) {
    float4 p = part[(size_t)ch * 16384 + g4];
    s.x += p.x; s.y += p.y; s.z += p.z; s.w += p.w;
  }
  float sq = s.x * s.x + s.y * s.y + s.z * s.z + s.w * s.w;
#pragma unroll
  for (int m = 4; m >= 1; m >>= 1) sq += __shfl_xor(sq, m, 8);
  float scale = sq / ((1.f + sq) * (sqrtf(sq) + 1e-6f));
  float4 r = make_float4(s.x * scale, s.y * scale, s.z * scale, s.w * scale);
  if (prev) {
    float4 p = prev[g4];
    r.x += p.x; r.y += p.y; r.z += p.z; r.w += p.w;
  }
  out[g4] = r;
}

extern "C" void kernel_launch(void* const* d_in, const int* in_sizes, int n_in,
                              void* d_out, int out_size, void* d_ws,
                              size_t ws_size, hipStream_t stream) {
  const float* x = (const float*)d_in[0];
  const float* W = (const float*)d_in[1];
  float* out = (float*)d_out;

  const size_t XP_FLOATS = 4ull * 2048 * 4 * 16 * 4;       // 2,097,152
  const size_t WP_FLOATS = 2048ull * 32 * 2 * 4 * 16 * 4;  // 33,554,432

  float* v1 = (float*)d_ws;
  float* vsum = v1 + 65536;
  float* partial = vsum + 65536;

  const int chunks = 128;  // mfma_pass6 requires NC==16
  bool packed_path =
      (131072 + (size_t)chunks * 65536 + XP_FLOATS + WP_FLOATS) * 4 <= ws_size;

  if (packed_path) {
    uint4* XP = (uint4*)(partial + (size_t)chunks * 65536);
    uint4* WP = XP + XP_FLOATS / 4;
    const int NC = N_ / chunks;  // 16
    const int cq = chunks / 4;   // 32
    dim3 grid(chunks, 2);

    prep_all<<<8704, 256, 0, stream>>>(W, x, WP, XP);

    mfma_pass6<1><<<grid, 1024, 0, stream>>>(XP, WP, nullptr, partial, NC);
    reduce_stageA<<<256, 256, 0, stream>>>((float4*)partial, cq);
    reduce_stageB<<<64, 256, 0, stream>>>((const float4*)partial, cq, nullptr,
                                          (float4*)v1);
    mfma_pass6<0><<<grid, 1024, 0, stream>>>(XP, WP, v1, partial, NC);
    reduce_stageA<<<256, 256, 0, stream>>>((float4*)partial, cq);
    reduce_stageB<<<64, 256, 0, stream>>>((const float4*)partial, cq,
                                          (const float4*)v1, (float4*)vsum);
    mfma_pass6<0><<<grid, 1024, 0, stream>>>(XP, WP, vsum, partial, NC);
    reduce_stageA<<<256, 256, 0, stream>>>((float4*)partial, cq);
    reduce_stageB<<<64, 256, 0, stream>>>((const float4*)partial, cq, nullptr,
                                          (float4*)out);
  } else {
    int fchunks = 128;
    while (fchunks > 1 && (131072 + (size_t)fchunks * 65536) * 4 > ws_size)
      fchunks >>= 1;
    int NC = N_ / fchunks;
    dim3 grid(fchunks, 4);

    mfma_pass_fb<1><<<grid, 512, 0, stream>>>(x, W, nullptr, partial, NC);
    reduce_squash<<<64, 256, 0, stream>>>((const float4*)partial, fchunks,
                                          nullptr, (float4*)v1);
    mfma_pass_fb<0><<<grid, 512, 0, stream>>>(x, W, v1, partial, NC);
    reduce_squash<<<64, 256, 0, stream>>>((const float4*)partial, fchunks,
                                          (const float4*)v1, (float4*)vsum);
    mfma_pass_fb<0><<<grid, 512, 0, stream>>>(x, W, vsum, partial, NC);
    reduce_squash<<<64, 256, 0, stream>>>((const float4*)partial, fchunks,
                                          nullptr, (float4*)out);
  }
}